// Round 3
// baseline (632.098 us; speedup 1.0000x reference)
//
#include <hip/hip_runtime.h>

// ---------------------------------------------------------------------------
// r[b,v] = sum_c (feats[b,c,v] - m[c,v]) / s[c,v] * weights[v,c] + bias[v]
// feats per scale k: GEMM  fmap_k (B*Ck x n^2)  @  prf_k^T (n^2 x V)
// Fused: epilogue multiplies feats tile by w'[c,v]=weights[v,c]/s[c,v],
// reduces over c within the block, atomicAdd into out (pre-initialized with
// off[v] = bias[v] - sum_c m[c,v]*w'[c,v]).
// ---------------------------------------------------------------------------

typedef float f32x4 __attribute__((ext_vector_type(4)));
typedef __bf16 bf16x8 __attribute__((ext_vector_type(8)));

#define BM 128
#define BN 128
#define BK 64
#define LDK 72          // LDS row pitch in bf16 elems (64 + 8 pad -> 2-way banks)
#define V_DIM 512
#define C_TOT 960
#define B_DIM 128

static __device__ __forceinline__ unsigned short f2bf(float f) {
  // round-to-nearest-even fp32 -> bf16
  unsigned u = __float_as_uint(f);
  u += 0x7FFFu + ((u >> 16) & 1u);
  return (unsigned short)(u >> 16);
}

__global__ __launch_bounds__(256, 2)
void fused_pool_readout(const float* __restrict__ fmap,   // [B*Ck, K]
                        const float* __restrict__ prf,    // [V, K]
                        const float* __restrict__ weights,// [V, C_TOT]
                        const float* __restrict__ fs,     // [C_TOT, V]
                        float* __restrict__ out,          // [B, V]
                        int Ck, int K, int Coff)
{
  __shared__ unsigned short lds_a[BM * LDK];
  __shared__ unsigned short lds_b[BN * LDK];

  const int tid  = threadIdx.x;
  const int lane = tid & 63;
  const int wid  = tid >> 6;     // 0..3
  const int wm   = wid >> 1;     // 0..1 : 64-row half of M-tile
  const int wn   = wid & 1;      // 0..1 : 64-col half of N-tile

  const long bm = (long)blockIdx.y * BM;   // row offset in M = B*Ck
  const int  bn = blockIdx.x * BN;         // col offset in V

  f32x4 acc[4][4];
#pragma unroll
  for (int i = 0; i < 4; ++i)
#pragma unroll
    for (int j = 0; j < 4; ++j)
      acc[i][j] = f32x4{0.f, 0.f, 0.f, 0.f};

  const int  nsteps = (K + BK - 1) / BK;
  const bool vec4   = ((K & 3) == 0);   // rows 16B-aligned & chunks clean

  for (int ks = 0; ks < nsteps; ++ks) {
    const int kbase = ks * BK;
    __syncthreads();   // protect LDS from previous iteration's readers

    // ---- stage A (fmap rows) and B (prf rows) into LDS as bf16, zero-pad K
    // 128 rows x 16 four-float chunks = 2048 chunks per tile; 8 per thread.
#pragma unroll 4
    for (int i = 0; i < 8; ++i) {
      const int chunk = tid + i * 256;
      const int row   = chunk >> 4;
      const int c4    = (chunk & 15) << 2;
      const int gk    = kbase + c4;
      float a[4] = {0.f, 0.f, 0.f, 0.f};
      float b[4] = {0.f, 0.f, 0.f, 0.f};
      const float* ap = fmap + (bm + row) * (long)K + gk;
      const float* bp = prf  + (long)(bn + row) * K + gk;
      if (vec4) {
        if (gk + 4 <= K) {
          const f32x4 va = *(const f32x4*)ap;
          const f32x4 vb = *(const f32x4*)bp;
          a[0] = va[0]; a[1] = va[1]; a[2] = va[2]; a[3] = va[3];
          b[0] = vb[0]; b[1] = vb[1]; b[2] = vb[2]; b[3] = vb[3];
        }
      } else {
#pragma unroll
        for (int e = 0; e < 4; ++e)
          if (gk + e < K) { a[e] = ap[e]; b[e] = bp[e]; }
      }
      unsigned short* wa = &lds_a[row * LDK + c4];
      unsigned short* wb = &lds_b[row * LDK + c4];
#pragma unroll
      for (int e = 0; e < 4; ++e) { wa[e] = f2bf(a[e]); wb[e] = f2bf(b[e]); }
    }
    __syncthreads();

    // ---- MFMA over the two K=32 sub-chunks of this BK=64 step
#pragma unroll
    for (int kc = 0; kc < 2; ++kc) {
      const int kb = kc * 32 + ((lane >> 4) << 3);   // 8 consecutive k / lane
      bf16x8 af[4], bfr[4];
#pragma unroll
      for (int i = 0; i < 4; ++i)
        af[i] = *(const bf16x8*)&lds_a[(wm * 64 + i * 16 + (lane & 15)) * LDK + kb];
#pragma unroll
      for (int j = 0; j < 4; ++j)
        bfr[j] = *(const bf16x8*)&lds_b[(wn * 64 + j * 16 + (lane & 15)) * LDK + kb];
#pragma unroll
      for (int i = 0; i < 4; ++i)
#pragma unroll
        for (int j = 0; j < 4; ++j)
          acc[i][j] = __builtin_amdgcn_mfma_f32_16x16x32_bf16(af[i], bfr[j],
                                                              acc[i][j], 0, 0, 0);
    }
  }

  // ---- epilogue: per-wave 64x64 feats sub-tile; all 64 m-rows share one b
  // (Ck is a multiple of 64 and wave base is 64-aligned).
  // C/D layout: frag row = (lane>>4)*4 + reg, frag col = lane&15   [m89]
  const long mbase = bm + wm * 64;
  const int  bidx  = (int)(mbase / Ck);
  const int  cbase = (int)(mbase % Ck) + Coff;
  const int  lrow  = ((lane >> 4) << 2);
  const int  lcol  = lane & 15;

#pragma unroll
  for (int j = 0; j < 4; ++j) {
    const int v = bn + wn * 64 + j * 16 + lcol;
    float s = 0.f;
#pragma unroll
    for (int i = 0; i < 4; ++i) {
      const int cg = cbase + i * 16 + lrow;
#pragma unroll
      for (int r = 0; r < 4; ++r) {
        const float w  = weights[(long)v * C_TOT + cg + r];
        const float sv = fs[(long)(cg + r) * V_DIM + v];
        s += acc[i][j][r] * (w / sv);
      }
    }
    // sum the 4 row-groups (lanes xor 16/32 hold same v, different rows)
    s += __shfl_xor(s, 16);
    s += __shfl_xor(s, 32);
    if (lane < 16)
      atomicAdd(&out[(long)bidx * V_DIM + v], s);
  }
}

// out[b,v] = bias[v] - sum_c m[c,v] * weights[v,c] / s[c,v]
__global__ void init_out_kernel(const float* __restrict__ weights,
                                const float* __restrict__ bias,
                                const float* __restrict__ fm,
                                const float* __restrict__ fs,
                                float* __restrict__ out)
{
  const int v = blockIdx.x * blockDim.x + threadIdx.x;
  if (v >= V_DIM) return;
  float acc = bias[v];
  for (int c = 0; c < C_TOT; ++c) {
    acc -= fm[(long)c * V_DIM + v] * weights[(long)v * C_TOT + c]
           / fs[(long)c * V_DIM + v];
  }
#pragma unroll 4
  for (int b = 0; b < B_DIM; ++b)
    out[(long)b * V_DIM + v] = acc;
}

extern "C" void kernel_launch(void* const* d_in, const int* in_sizes, int n_in,
                              void* d_out, int out_size, void* d_ws, size_t ws_size,
                              hipStream_t stream)
{
  // setup_inputs() dict order is INTERLEAVED: fmap0,prf0,fmap1,prf1,...
  const float* fmap0   = (const float*)d_in[0];
  const float* prf0    = (const float*)d_in[1];
  const float* fmap1   = (const float*)d_in[2];
  const float* prf1    = (const float*)d_in[3];
  const float* fmap2   = (const float*)d_in[4];
  const float* prf2    = (const float*)d_in[5];
  const float* fmap3   = (const float*)d_in[6];
  const float* prf3    = (const float*)d_in[7];
  const float* weights = (const float*)d_in[8];
  const float* bias    = (const float*)d_in[9];
  const float* fm      = (const float*)d_in[10];
  const float* fs      = (const float*)d_in[11];
  float* out = (float*)d_out;

  // 1) initialize out with the constant term (stream-ordered before GEMMs)
  init_out_kernel<<<dim3(2), dim3(256), 0, stream>>>(weights, bias, fm, fs, out);

  // 2) one fused GEMM+readout per scale
  struct Scale { const float* fmap; const float* prf; int Ck, K, Coff; };
  const Scale sc[4] = {
    {fmap0, prf0,  64, 56 * 56,   0},
    {fmap1, prf1, 128, 28 * 28,  64},
    {fmap2, prf2, 256, 14 * 14, 192},
    {fmap3, prf3, 512,  7 * 7,  448},
  };
  for (int k = 0; k < 4; ++k) {
    const int M = B_DIM * sc[k].Ck;
    dim3 grid(V_DIM / BN, M / BM);
    fused_pool_readout<<<grid, dim3(256), 0, stream>>>(
        sc[k].fmap, sc[k].prf, weights, fs, out,
        sc[k].Ck, sc[k].K, sc[k].Coff);
  }
}

// Round 4
// 193.395 us; speedup vs baseline: 3.2684x; 3.2684x over previous
//
#include <hip/hip_runtime.h>

// ---------------------------------------------------------------------------
// r[b,v] = sum_c (feats[b,c,v] - m[c,v]) / s[c,v] * weights[v,c] + bias[v]
// feats per scale k: GEMM  fmap_k (B*Ck x K=n^2)  @  prf_k^T (K x V)
// Fused: epilogue multiplies the feats tile by w'[c,v] = weights[v,c]/s[c,v]
// and atomicAdds the c-reduced partials into out, which is pre-initialized
// with off[v] = bias[v] - sum_c m[c,v]*w'[c,v].
// Split-K via grid.z (atomics make it free) for >=3 blocks/CU overlap.
// ---------------------------------------------------------------------------

typedef float f32x4 __attribute__((ext_vector_type(4)));
typedef f32x4 __attribute__((aligned(4))) f32x4u;   // 4B-aligned vector load (K=49 rows)
typedef __bf16 bf16x8 __attribute__((ext_vector_type(8)));
typedef unsigned int u32x2 __attribute__((ext_vector_type(2)));

#define BM 128
#define BN 128
#define BK 64
#define LDK 72          // LDS row pitch in bf16 elems (64 + 8 pad -> 2-way banks)
#define V_DIM 512
#define C_TOT 960
#define B_DIM 128

// pack two fp32 -> two bf16 (RNE) in one u32
static __device__ __forceinline__ unsigned f2bf2(float lo, float hi) {
  unsigned ul = __float_as_uint(lo); ul += 0x7FFFu + ((ul >> 16) & 1u);
  unsigned uh = __float_as_uint(hi); uh += 0x7FFFu + ((uh >> 16) & 1u);
  return (ul >> 16) | (uh & 0xFFFF0000u);
}

__global__ __launch_bounds__(256, 3)
void fused_pool_readout(const float* __restrict__ fmap,   // [B*Ck, K]
                        const float* __restrict__ prf,    // [V, K]
                        const float* __restrict__ weights,// [V, C_TOT]
                        const float* __restrict__ fs,     // [C_TOT, V]
                        const float* __restrict__ wp,     // [C_TOT, V] or null
                        float* __restrict__ out,          // [B, V]
                        int Ck, int K, int Coff,
                        int nsteps_tot, int kchunks)
{
  __shared__ unsigned short lds_a[BM * LDK];
  __shared__ unsigned short lds_b[BN * LDK];

  const int tid  = threadIdx.x;
  const int lane = tid & 63;
  const int wid  = tid >> 6;     // 0..3
  const int wm   = wid >> 1;     // 0..1 : 64-row half of M-tile
  const int wn   = wid & 1;      // 0..1 : 64-col half of N-tile

  const long bm = (long)blockIdx.y * BM;   // row offset in M = B*Ck
  const int  bn = blockIdx.x * BN;         // col offset in V

  // split-K chunk [s0, s0+scnt) of BK-steps
  const int z    = blockIdx.z;
  const int qb   = nsteps_tot / kchunks;
  const int rb   = nsteps_tot % kchunks;
  const int s0   = z * qb + (z < rb ? z : rb);
  const int scnt = qb + (z < rb ? 1 : 0);

  f32x4 acc[4][4];
#pragma unroll
  for (int i = 0; i < 4; ++i)
#pragma unroll
    for (int j = 0; j < 4; ++j)
      acc[i][j] = f32x4{0.f, 0.f, 0.f, 0.f};

  for (int ks = s0; ks < s0 + scnt; ++ks) {
    const int kbase = ks * BK;
    __syncthreads();   // protect LDS from previous iteration's readers

    // ---- stage A (fmap rows) and B (prf rows) into LDS as bf16, zero-pad K
    // 128 rows x 16 four-float chunks per tile; 8 chunks (A+B) per thread.
#pragma unroll 4
    for (int i = 0; i < 8; ++i) {
      const int chunk = tid + i * 256;
      const int row   = chunk >> 4;
      const int c4    = (chunk & 15) << 2;
      const int gk    = kbase + c4;
      float a0=0.f, a1=0.f, a2=0.f, a3=0.f;
      float b0=0.f, b1=0.f, b2=0.f, b3=0.f;
      const float* ap = fmap + (bm + row) * (long)K + gk;
      const float* bp = prf  + (long)(bn + row) * K + gk;
      if (gk + 4 <= K) {
        const f32x4u va = *(const f32x4u*)ap;
        const f32x4u vb = *(const f32x4u*)bp;
        a0 = va[0]; a1 = va[1]; a2 = va[2]; a3 = va[3];
        b0 = vb[0]; b1 = vb[1]; b2 = vb[2]; b3 = vb[3];
      } else if (gk < K) {                 // ragged tail (K=49 only)
        a0 = ap[0]; b0 = bp[0];
        if (gk + 1 < K) { a1 = ap[1]; b1 = bp[1]; }
        if (gk + 2 < K) { a2 = ap[2]; b2 = bp[2]; }
        if (gk + 3 < K) { a3 = ap[3]; b3 = bp[3]; }
      }
      *(u32x2*)&lds_a[row * LDK + c4] = u32x2{f2bf2(a0, a1), f2bf2(a2, a3)};
      *(u32x2*)&lds_b[row * LDK + c4] = u32x2{f2bf2(b0, b1), f2bf2(b2, b3)};
    }
    __syncthreads();

    // ---- MFMA over the two K=32 sub-chunks of this BK=64 step
#pragma unroll
    for (int kc = 0; kc < 2; ++kc) {
      const int kb = kc * 32 + ((lane >> 4) << 3);   // 8 consecutive k / lane
      bf16x8 af[4], bfr[4];
#pragma unroll
      for (int i = 0; i < 4; ++i)
        af[i] = *(const bf16x8*)&lds_a[(wm * 64 + i * 16 + (lane & 15)) * LDK + kb];
#pragma unroll
      for (int j = 0; j < 4; ++j)
        bfr[j] = *(const bf16x8*)&lds_b[(wn * 64 + j * 16 + (lane & 15)) * LDK + kb];
#pragma unroll
      for (int i = 0; i < 4; ++i)
#pragma unroll
        for (int j = 0; j < 4; ++j)
          acc[i][j] = __builtin_amdgcn_mfma_f32_16x16x32_bf16(af[i], bfr[j],
                                                              acc[i][j], 0, 0, 0);
    }
  }

  // ---- epilogue: per-wave 64x64 feats sub-tile; all 64 m-rows share one b
  // (Ck multiple of 64, wave base 64-aligned).
  // C/D layout: frag row = (lane>>4)*4 + reg, frag col = lane&15   [m89]
  const long mbase = bm + wm * 64;
  const int  bidx  = (int)(mbase / Ck);
  const int  cbase = (int)(mbase % Ck) + Coff;
  const int  lrow  = ((lane >> 4) << 2);
  const int  lcol  = lane & 15;

#pragma unroll
  for (int j = 0; j < 4; ++j) {
    const int v = bn + wn * 64 + j * 16 + lcol;
    float s = 0.f;
#pragma unroll
    for (int i = 0; i < 4; ++i) {
      const int cg = cbase + i * 16 + lrow;
#pragma unroll
      for (int r = 0; r < 4; ++r) {
        float wfac;
        if (wp)  wfac = wp[(long)(cg + r) * V_DIM + v];
        else     wfac = weights[(long)v * C_TOT + cg + r]
                        / fs[(long)(cg + r) * V_DIM + v];
        s += acc[i][j][r] * wfac;
      }
    }
    // fold the 4 row-groups (lanes xor 16/32 hold same v, different c rows)
    s += __shfl_xor(s, 16);
    s += __shfl_xor(s, 32);
    if (lane < 16)
      atomicAdd(&out[(long)bidx * V_DIM + v], s);
  }
}

// wp[c*V+v] = weights[v*C+c] / fs[c*V+v]
__global__ void prep_wprime(const float* __restrict__ weights,
                            const float* __restrict__ fs,
                            float* __restrict__ wp)
{
  const int idx = blockIdx.x * 256 + threadIdx.x;   // = c*V_DIM + v
  if (idx >= C_TOT * V_DIM) return;
  const int c = idx >> 9;
  const int v = idx & (V_DIM - 1);
  wp[idx] = weights[(long)v * C_TOT + c] / fs[idx];
}

// out[b,v] = bias[v] - sum_c m[c,v]*w'[c,v]   (one block per v, parallel c)
__global__ void prep_off(const float* __restrict__ weights,
                         const float* __restrict__ bias,
                         const float* __restrict__ fm,
                         const float* __restrict__ fs,
                         const float* __restrict__ wp,   // may be null
                         float* __restrict__ out)
{
  __shared__ float red[4];
  const int v = blockIdx.x;
  const int t = threadIdx.x;
  float s = 0.f;
  for (int c = t; c < C_TOT; c += 256) {
    const long i = (long)c * V_DIM + v;
    const float w = wp ? wp[i] : weights[(long)v * C_TOT + c] / fs[i];
    s += fm[i] * w;
  }
#pragma unroll
  for (int o = 32; o; o >>= 1) s += __shfl_down(s, o);
  if ((t & 63) == 0) red[t >> 6] = s;
  __syncthreads();
  if (t < B_DIM) {
    const float off = bias[v] - (red[0] + red[1] + red[2] + red[3]);
    out[(long)t * V_DIM + v] = off;
  }
}

extern "C" void kernel_launch(void* const* d_in, const int* in_sizes, int n_in,
                              void* d_out, int out_size, void* d_ws, size_t ws_size,
                              hipStream_t stream)
{
  // setup_inputs() dict order: fmap0,prf0,fmap1,prf1,fmap2,prf2,fmap3,prf3,
  //                            weights,bias,features_m,features_s
  const float* fmap0   = (const float*)d_in[0];
  const float* prf0    = (const float*)d_in[1];
  const float* fmap1   = (const float*)d_in[2];
  const float* prf1    = (const float*)d_in[3];
  const float* fmap2   = (const float*)d_in[4];
  const float* prf2    = (const float*)d_in[5];
  const float* fmap3   = (const float*)d_in[6];
  const float* prf3    = (const float*)d_in[7];
  const float* weights = (const float*)d_in[8];
  const float* bias    = (const float*)d_in[9];
  const float* fm      = (const float*)d_in[10];
  const float* fs      = (const float*)d_in[11];
  float* out = (float*)d_out;

  // 0) precompute w' into workspace when it fits (1.97 MB); else divide inline
  float* wp = nullptr;
  if (ws_size >= (size_t)C_TOT * V_DIM * sizeof(float)) {
    wp = (float*)d_ws;
    prep_wprime<<<dim3((C_TOT * V_DIM + 255) / 256), dim3(256), 0, stream>>>(
        weights, fs, wp);
  }

  // 1) initialize out with the constant term (stream-ordered before GEMMs)
  prep_off<<<dim3(V_DIM), dim3(256), 0, stream>>>(weights, bias, fm, fs, wp, out);

  // 2) one fused GEMM+readout per scale; split-K for >=3 blocks/CU
  struct Scale { const float* fmap; const float* prf; int Ck, K, Coff, kchunks; };
  const Scale sc[4] = {
    {fmap0, prf0,  64, 56 * 56,   0, 3},   // 49 steps -> 17/16/16, 768 blocks
    {fmap1, prf1, 128, 28 * 28,  64, 2},   // 13 steps -> 7/6,     1024 blocks
    {fmap2, prf2, 256, 14 * 14, 192, 1},   //  4 steps,            1024 blocks
    {fmap3, prf3, 512,  7 * 7,  448, 1},   //  1 step,             2048 blocks
  };
  for (int k = 0; k < 4; ++k) {
    const int M = B_DIM * sc[k].Ck;
    const int nsteps = (sc[k].K + BK - 1) / BK;
    dim3 grid(V_DIM / BN, M / BM, sc[k].kchunks);
    fused_pool_readout<<<grid, dim3(256), 0, stream>>>(
        sc[k].fmap, sc[k].prf, weights, fs, wp, out,
        sc[k].Ck, sc[k].K, sc[k].Coff, nsteps, sc[k].kchunks);
  }
}